// Round 7
// baseline (641.086 us; speedup 1.0000x reference)
//
#include <hip/hip_runtime.h>
#include <stdint.h>

#define NN 8192
#define DD 512
#define EE 131072
#define BBATCH 16
#define NPG 512
#define SSEL 128
#define LL 3

typedef unsigned short u16;
typedef __bf16 bf16x8 __attribute__((ext_vector_type(8)));
typedef float f32x4 __attribute__((ext_vector_type(4)));
typedef float f32x2 __attribute__((ext_vector_type(2)));
typedef u16 u16x8 __attribute__((ext_vector_type(8)));

__device__ __forceinline__ float bf2f(u16 u) {
    union { unsigned i; float f; } v; v.i = ((unsigned)u) << 16; return v.f;
}
__device__ __forceinline__ u16 f2bf(float f) {
    union { unsigned i; float f; } v; v.f = f;
    unsigned i = v.i;
    return (u16)((i + 0x7FFFu + ((i >> 16) & 1u)) >> 16);  // RNE
}

// pack two fp32 -> packed bf16x2 in one uint (lo = s0, hi = s1)
__device__ __forceinline__ unsigned pk_bf16(float s0, float s1) {
#if __has_builtin(__builtin_amdgcn_cvt_pk_bf16_f32)
    typedef __bf16 bf16x2 __attribute__((ext_vector_type(2)));
    union { bf16x2 v; unsigned u; } r;
    r.v = __builtin_amdgcn_cvt_pk_bf16_f32(s0, s1);
    return r.u;
#else
    unsigned r0 = __float_as_uint(s0);
    r0 = (r0 + 0x7FFFu + ((r0 >> 16) & 1u)) >> 16;
    unsigned r1 = __float_as_uint(s1);
    r1 = (r1 + 0x7FFFu + ((r1 >> 16) & 1u)) & 0xffff0000u;
    return r0 | r1;
#endif
}

// async global->LDS, 16B per lane, LDS dest = wave-uniform base + lane*16
__device__ __forceinline__ void async_cp16(const u16* g, u16* l) {
    __builtin_amdgcn_global_load_lds(
        (const __attribute__((address_space(1))) unsigned int*)g,
        (__attribute__((address_space(3))) unsigned int*)l, 16, 0, 0);
}

// combine 4 bf16 pairs: relu(a + b) -> 2 packed bf16x2 words
__device__ __forceinline__ uint2 combine4(uint2 a, uint2 b) {
    uint2 r;
    unsigned wa[2] = {a.x, a.y}, wb[2] = {b.x, b.y};
    unsigned ro[2];
    #pragma unroll
    for (int q = 0; q < 2; ++q) {
        f32x2 s;
        s[0] = __uint_as_float(wa[q] << 16) + __uint_as_float(wb[q] << 16);
        s[1] = __uint_as_float(wa[q] & 0xffff0000u) +
               __uint_as_float(wb[q] & 0xffff0000u);
        s[0] = fmaxf(s[0], 0.f);
        s[1] = fmaxf(s[1], 0.f);
        ro[q] = pk_bf16(s[0], s[1]);
    }
    r.x = ro[0];
    r.y = ro[1];
    return r;
}

// ---------------- LayerNorm (+ optional residual-add + agg zeroing)
// 4 rows per 256-thr block (wave per row)
__global__ __launch_bounds__(256) void ln_fused(const float* __restrict__ xin,
                                                float* __restrict__ agg_io,
                                                float* __restrict__ xout,
                                                const float* __restrict__ g,
                                                const float* __restrict__ b,
                                                u16* __restrict__ h, int doAdd) {
    int row = blockIdx.x * 4 + (threadIdx.x >> 6);
    int lane = threadIdx.x & 63;
    const f32x4* x4 = (const f32x4*)(xin + (size_t)row * DD);
    f32x4 p = x4[lane * 2], q = x4[lane * 2 + 1];
    if (doAdd) {
        const f32x4* a4 = (const f32x4*)(agg_io + (size_t)row * DD);
        f32x4 pa = a4[lane * 2], qa = a4[lane * 2 + 1];
        #pragma unroll
        for (int i = 0; i < 4; ++i) { p[i] += pa[i]; q[i] += qa[i]; }
    }
    if (agg_io) {
        f32x4 z;
        #pragma unroll
        for (int i = 0; i < 4; ++i) z[i] = 0.f;
        f32x4* a4 = (f32x4*)(agg_io + (size_t)row * DD);
        a4[lane * 2] = z;
        a4[lane * 2 + 1] = z;
    }
    f32x4* xo = (f32x4*)(xout + (size_t)row * DD);
    xo[lane * 2] = p;
    xo[lane * 2 + 1] = q;
    float v[8];
    v[0] = p[0]; v[1] = p[1]; v[2] = p[2]; v[3] = p[3];
    v[4] = q[0]; v[5] = q[1]; v[6] = q[2]; v[7] = q[3];
    float s = 0.f, sq = 0.f;
    #pragma unroll
    for (int i = 0; i < 8; ++i) { s += v[i]; sq += v[i] * v[i]; }
    #pragma unroll
    for (int o = 32; o >= 1; o >>= 1) { s += __shfl_xor(s, o); sq += __shfl_xor(sq, o); }
    float mu = s * (1.f / DD);
    float var = sq * (1.f / DD) - mu * mu;
    float rs = rsqrtf(var + 1e-5f);
    int kb = lane * 8;
    u16x8 o8;
    #pragma unroll
    for (int i = 0; i < 8; ++i) o8[i] = f2bf((v[i] - mu) * rs * g[kb + i] + b[kb + i]);
    *(u16x8*)(h + (size_t)row * DD + kb) = o8;
}

// ---------------- counting sort by dst
__global__ void hist_kernel(const int* __restrict__ dst, int* __restrict__ cnt) {
    int e = blockIdx.x * 256 + threadIdx.x;
    if (e < EE) atomicAdd(&cnt[dst[e]], 1);
}

__global__ __launch_bounds__(1024) void scan_kernel(const int* __restrict__ cnt,
                                                    int* __restrict__ off,
                                                    int* __restrict__ cur) {
    __shared__ int part[1024];
    int t = threadIdx.x;
    int base = t * 8;
    int loc[8]; int s = 0;
    #pragma unroll
    for (int i = 0; i < 8; ++i) { loc[i] = s; s += cnt[base + i]; }
    part[t] = s;
    __syncthreads();
    for (int o = 1; o < 1024; o <<= 1) {
        int v = part[t];
        int u = (t >= o) ? part[t - o] : 0;
        __syncthreads();
        part[t] = v + u;
        __syncthreads();
    }
    int bx = (t > 0) ? part[t - 1] : 0;
    #pragma unroll
    for (int i = 0; i < 8; ++i) { off[base + i] = bx + loc[i]; cur[base + i] = bx + loc[i]; }
    if (t == 0) off[NN] = part[1023];
}

__global__ void scatter_kernel(const int* __restrict__ src, const int* __restrict__ dst,
                               int* __restrict__ cur, int* __restrict__ ssrc,
                               int* __restrict__ sdst) {
    int e = blockIdx.x * 256 + threadIdx.x;
    if (e < EE) {
        int d = dst[e];
        int p = atomicAdd(&cur[d], 1);
        ssrc[p] = src[e];
        sdst[p] = d;
    }
}

// ---------------- 5x fused cvt+transpose for 512x512 fp32 mats -> bf16 [N][K]
struct CvtJobs {
    const float* s[5];
    u16* d[5];
};
__global__ __launch_bounds__(256) void cvt_t5_kernel(CvtJobs jobs) {
    __shared__ u16 tile[32][33];
    const float* src = jobs.s[blockIdx.z];
    u16* dstp = jobs.d[blockIdx.z];
    int bk = blockIdx.x * 32, bn = blockIdx.y * 32;
    int tx = threadIdx.x & 31, ty = threadIdx.x >> 5;  // 32 x 8
    #pragma unroll
    for (int r = 0; r < 32; r += 8)
        tile[ty + r][tx] = f2bf(src[(size_t)(bk + ty + r) * 512 + bn + tx]);
    __syncthreads();
    #pragma unroll
    for (int r = 0; r < 32; r += 8)
        dstp[(size_t)(bn + ty + r) * 512 + bk + tx] = tile[tx][ty + r];
}

// W1 fp32 [L][1024][512] -> Wcat^T bf16 [L][1024 rows][512]:
// rows 0..511 = (W1a - W1b)^T ; rows 512..1023 = W1b^T. z = layer.
__global__ __launch_bounds__(256) void cvt_w1_kernel(const float* __restrict__ W1g,
                                                     u16* __restrict__ dstg) {
    __shared__ u16 tile[32][33];
    const float* W1 = W1g + (size_t)blockIdx.z * 1024 * 512;
    u16* dstp = dstg + (size_t)blockIdx.z * 1024 * 512;
    int bk = blockIdx.x * 32, bn = blockIdx.y * 32;
    int tx = threadIdx.x & 31, ty = threadIdx.x >> 5;
    #pragma unroll
    for (int r = 0; r < 32; r += 8) {
        int k = bk + ty + r, n = bn + tx;
        float v = (n < 512) ? (W1[(size_t)k * 512 + n] - W1[(size_t)(k + 512) * 512 + n])
                            : W1[(size_t)(k + 512) * 512 + (n - 512)];
        tile[ty + r][tx] = f2bf(v);
    }
    __syncthreads();
    #pragma unroll
    for (int r = 0; r < 32; r += 8)
        dstp[(size_t)(bn + ty + r) * 512 + bk + tx] = tile[tx][ty + r];
}

// ---------------- async MFMA GEMM, 128x128 tile, 256 threads (2x2 waves)
// EMODE 0: relu(acc+bias)->bf16 ; 1: acc+bias+resid->fp32 ; 2: acc->bf16 ;
// EMODE 3: acc + (col<512 ? bias[col] : 0) -> bf16   (P-GEMM, folds b1 into Pa)
template <int EMODE>
__global__ __launch_bounds__(256) void gemm_async(
    const u16* __restrict__ A, const u16* __restrict__ BT,
    const float* __restrict__ bias, const float* __restrict__ resid,
    void* __restrict__ Cout, int K, int ldc) {
    __shared__ u16 lA[128 * 64];
    __shared__ u16 lB[128 * 64];
    const int tid = threadIdx.x;
    const int lane = tid & 63, wave = tid >> 6;
    const int wm = wave & 1, wn = wave >> 1;
    const int quad = lane >> 4, lm = lane & 15;
    const int tileM = blockIdx.x, tileN = blockIdx.y;

    const int g = (lane & 7) ^ (lane >> 3);
    const u16* ap[4];
    const u16* bp[4];
    u16* lad[4];
    u16* lbd[4];
    #pragma unroll
    for (int j = 0; j < 4; ++j) {
        int seg = wave * 4 + j;
        int rA = tileM * 128 + seg * 8 + (lane >> 3);
        int rB = tileN * 128 + seg * 8 + (lane >> 3);
        ap[j] = A + (size_t)rA * K + g * 8;
        bp[j] = BT + (size_t)rB * K + g * 8;
        lad[j] = lA + seg * 512;
        lbd[j] = lB + seg * 512;
    }

    f32x4 acc[4][4];
    #pragma unroll
    for (int mt = 0; mt < 4; ++mt)
        #pragma unroll
        for (int nt = 0; nt < 4; ++nt)
            #pragma unroll
            for (int j = 0; j < 4; ++j) acc[mt][nt][j] = 0.f;

    for (int kb = 0; kb < K; kb += 64) {
        #pragma unroll
        for (int j = 0; j < 4; ++j) {
            async_cp16(ap[j], lad[j]);
            async_cp16(bp[j], lbd[j]);
            ap[j] += 64;
            bp[j] += 64;
        }
        __syncthreads();
        #pragma unroll
        for (int kk = 0; kk < 64; kk += 32) {
            bf16x8 af[4], bfr[4];
            int gbase = (kk >> 3) + quad;
            #pragma unroll
            for (int mt = 0; mt < 4; ++mt) {
                int row = wm * 64 + mt * 16 + lm;
                af[mt] = *(const bf16x8*)(lA + row * 64 + ((gbase ^ (row & 7)) << 3));
            }
            #pragma unroll
            for (int nt = 0; nt < 4; ++nt) {
                int row = wn * 64 + nt * 16 + lm;
                bfr[nt] = *(const bf16x8*)(lB + row * 64 + ((gbase ^ (row & 7)) << 3));
            }
            #pragma unroll
            for (int mt = 0; mt < 4; ++mt)
                #pragma unroll
                for (int nt = 0; nt < 4; ++nt)
                    acc[mt][nt] = __builtin_amdgcn_mfma_f32_16x16x32_bf16(
                        af[mt], bfr[nt], acc[mt][nt], 0, 0, 0);
        }
        __syncthreads();
    }
    #pragma unroll
    for (int mt = 0; mt < 4; ++mt) {
        #pragma unroll
        for (int nt = 0; nt < 4; ++nt) {
            int col = tileN * 128 + wn * 64 + nt * 16 + lm;
            float bv;
            if (EMODE == 2) bv = 0.f;
            else if (EMODE == 3) bv = (col < 512) ? bias[col] : 0.f;
            else bv = bias[col];
            #pragma unroll
            for (int j = 0; j < 4; ++j) {
                int grow = tileM * 128 + wm * 64 + mt * 16 + quad * 4 + j;
                float v = acc[mt][nt][j] + bv;
                if (EMODE == 0) {
                    ((u16*)Cout)[(size_t)grow * ldc + col] = f2bf(fmaxf(v, 0.f));
                } else if (EMODE == 1) {
                    ((float*)Cout)[(size_t)grow * ldc + col] =
                        v + resid[(size_t)grow * ldc + col];
                } else {
                    ((u16*)Cout)[(size_t)grow * ldc + col] = f2bf(v);
                }
            }
        }
    }
}

// ---------------- fused edge GEMM, FULL-WIDTH 64 edges x 512 cols, 512 thr
// (8 waves = 8 N-slices, wave tile 64x64). K-step 32, dbuf lA/lB, one barrier
// per step; W2T(kb+1) asyncs hide under MFMA (R5/R6: FETCH 52MB, WRITE 20MB).
// Macro-row swizzle (R6): 0 bank conflicts, verified.
// Round-14: distance-2 REGISTER prefetch for the Pa/Pb gathers. R4/R6 both
// issued+consumed gathers within one step and drained vmcnt(0) -> ~700cy L3
// latency exposed EVERY step (16x in R6 = the 134 vs 112.8 regression). Now:
// step kb issues g(kb+2)->regs (uint2 x4 = 8 VGPR, static parity via full
// unroll); combine(kb+1) consumes g(kb+1) loaded a FULL step earlier (landed,
// wait-free); end-of-step wait is COUNTED vmcnt(2) - drains the 4 W2T asyncs,
// keeps the 2 gathers in flight across the barrier.
// Ledger (steady kb<14): enter 2 outstanding; +4 async +2 gather = 8;
// combine auto-wait vmcnt(6) [free]; end vmcnt(2). kb=14: end vmcnt(0).
//  * LDS: lA dbuf 2x4KB + lB dbuf 2x32KB + nid = 74KB -> 2 blocks/CU
//  * regs: ~60 arch + 64 AGPR acc -- MUST stay <=64 arch (occupancy cliff)
__global__ __launch_bounds__(512, 4) void gemm_edge(
    const u16* __restrict__ P, const int* __restrict__ ssrc,
    const int* __restrict__ sdst, const u16* __restrict__ W2T,
    const float* __restrict__ b2, float* __restrict__ agg) {
    __shared__ u16 smem[2 * 64 * 32 + 2 * 512 * 32];  // 73728 B
    __shared__ int nid_l[64];
    u16* lA = smem;                  // [2][64*32]
    u16* lB = smem + 2 * 64 * 32;    // [2][512*32]
    const int tid = threadIdx.x;
    const int lane = tid & 63, wave = tid >> 6;
    const int quad = lane >> 4, lm = lane & 15;
    const int ebase = blockIdx.x * 64;

    if (tid < 64) nid_l[tid] = sdst[ebase + tid];

    // combine assignment: edge row = tid>>3, 4-elem k-slice sub = tid&7
    const int crow = tid >> 3, sub = tid & 7;
    const int dn = sdst[ebase + crow];
    const int sn = ssrc[ebase + crow];
    const int aoff = dn * 1024 + sub * 4;        // + kb*32
    const int boff = sn * 1024 + 512 + sub * 4;  // + kb*32
    // lA write offset (elems), macro-row swizzled
    const int cwo = (crow >> 1) * 64 +
                    (((((crow & 1) << 2) + (sub >> 1)) ^ ((crow >> 1) & 7)) << 3) +
                    (sub & 1) * 4;

    // W2T staging source (pre-permuted so linear LDS dest = swizzled layout)
    const int slotw = (lane & 7) ^ ((lane >> 3) & 7);
    const int wrow0 = wave * 64 + 2 * (lane >> 3) + (slotw >> 2);  // + j*16
    const int wbase = wrow0 * 512 + (slotw & 3) * 8;  // elems; + j*8192 + kb*32
    const int lbo = wave * 2048;                      // LDS base (elems); + j*512

    // MFMA read swizzle offset (lane-constant: macro&7 = (lm>>1)&7)
    const int soff = (((((lm & 1) << 2) + quad) ^ ((lm >> 1) & 7)) << 3);

    f32x4 acc[4][4];
    #pragma unroll
    for (int mt = 0; mt < 4; ++mt)
        #pragma unroll
        for (int nt = 0; nt < 4; ++nt)
            #pragma unroll
            for (int j = 0; j < 4; ++j) acc[mt][nt][j] = 0.f;

    // gather staging regs, slot = kslot & 1 (static indices only)
    uint2 sa0, sb0, sa1, sb1;

    // prologue. Issue order matters for the counted vmcnt ledger:
    // g(0) [oldest] -> asyncs W2T(0) -> g(1) [newest]
    sa0 = *(const uint2*)(P + aoff);
    sb0 = *(const uint2*)(P + boff);
    __builtin_amdgcn_sched_barrier(0);
    #pragma unroll
    for (int j = 0; j < 4; ++j)
        async_cp16(W2T + wbase + j * 8192, lB + lbo + j * 512);
    __builtin_amdgcn_sched_barrier(0);
    sa1 = *(const uint2*)(P + aoff + 32);
    sb1 = *(const uint2*)(P + boff + 32);
    __builtin_amdgcn_sched_barrier(0);
    // combine(0): compiler auto-waits vmcnt(6) = just g(0)
    *(uint2*)(lA + cwo) = combine4(sa0, sb0);
    // drain W2T(0) asyncs + lA writes; keep g(1) in flight
    asm volatile("s_waitcnt vmcnt(2) lgkmcnt(0)" ::: "memory");
    __builtin_amdgcn_s_barrier();

    #pragma unroll
    for (int kb = 0; kb < 16; ++kb) {
        const int cur = kb & 1;
        const int nxt = cur ^ 1;
        const u16* lAc = lA + cur * 2048;
        const u16* lBc = lB + cur * 16384;
        // W2T(kb+1) asyncs first (older): land under the MFMA phase
        if (kb < 15) {
            #pragma unroll
            for (int j = 0; j < 4; ++j)
                async_cp16(W2T + wbase + j * 8192 + (kb + 1) * 32,
                           lB + nxt * 16384 + lbo + j * 512);
        }
        __builtin_amdgcn_sched_barrier(0);
        // g(kb+2) gathers (newer): stay in flight across this step's barrier.
        // Slot (kb+2)&1 == cur; combine(kb) consumed it last step -> free.
        if (kb < 14) {
            if (cur == 0) {
                sa0 = *(const uint2*)(P + aoff + (kb + 2) * 32);
                sb0 = *(const uint2*)(P + boff + (kb + 2) * 32);
            } else {
                sa1 = *(const uint2*)(P + aoff + (kb + 2) * 32);
                sb1 = *(const uint2*)(P + boff + (kb + 2) * 32);
            }
        }
        __builtin_amdgcn_sched_barrier(0);
        // MFMA on current buffers (macro-row swizzled reads, conflict-free)
        bf16x8 af[4], bfr[4];
        #pragma unroll
        for (int mt = 0; mt < 4; ++mt)
            af[mt] = *(const bf16x8*)(lAc + (mt * 8 + (lm >> 1)) * 64 + soff);
        #pragma unroll
        for (int nt = 0; nt < 4; ++nt)
            bfr[nt] = *(const bf16x8*)(lBc + (wave * 32 + nt * 8 + (lm >> 1)) * 64 +
                                       soff);
        #pragma unroll
        for (int mt = 0; mt < 4; ++mt)
            #pragma unroll
            for (int nt = 0; nt < 4; ++nt)
                acc[mt][nt] = __builtin_amdgcn_mfma_f32_16x16x32_bf16(
                    af[mt], bfr[nt], acc[mt][nt], 0, 0, 0);
        // combine(kb+1) from regs loaded a full step ago (slot nxt) -> lA[nxt]
        if (kb < 15) {
            uint2 ca = (nxt == 0) ? sa0 : sa1;
            uint2 cb = (nxt == 0) ? sb0 : sb1;
            *(uint2*)(lA + nxt * 2048 + cwo) = combine4(ca, cb);
        }
        // drain this step's W2T asyncs + lA/ds writes; keep g(kb+2) in flight
        if (kb < 14) {
            asm volatile("s_waitcnt vmcnt(2) lgkmcnt(0)" ::: "memory");
        } else {
            asm volatile("s_waitcnt vmcnt(0) lgkmcnt(0)" ::: "memory");
        }
        __builtin_amdgcn_s_barrier();
    }

    // epilogue: single pass; cbuf 64 x 520 (66.5KB, aliases smem)
    u16* cbuf = smem;
    #pragma unroll
    for (int nt = 0; nt < 4; ++nt) {
        int col = wave * 64 + nt * 16 + lm;
        float bv = b2[col];
        #pragma unroll
        for (int mt = 0; mt < 4; ++mt) {
            #pragma unroll
            for (int j2 = 0; j2 < 4; ++j2) {
                int row = mt * 16 + quad * 4 + j2;  // 0..63
                cbuf[row * 520 + col] = f2bf(fmaxf(acc[mt][nt][j2] + bv, 0.f));
            }
        }
    }
    __syncthreads();
    {
        int col = tid;  // 0..511
        int cur = nid_l[0];
        float run = bf2f(cbuf[col]);
        for (int r = 1; r < 64; ++r) {
            int nd = nid_l[r];
            float v = bf2f(cbuf[r * 520 + col]);
            if (nd != cur) {
                atomicMax((unsigned int*)&agg[(size_t)cur * DD + col],
                          __float_as_uint(run));
                cur = nd;
                run = v;
            } else {
                run = fmaxf(run, v);
            }
        }
        atomicMax((unsigned int*)&agg[(size_t)cur * DD + col],
                  __float_as_uint(run));
    }
}

// ---------------- gather selected rows with residual add: xs[i] = x[r] + agg[r]
__global__ __launch_bounds__(128) void gather_fused(const float* __restrict__ x,
                                                    const float* __restrict__ agg,
                                                    const int* __restrict__ sel,
                                                    float* __restrict__ xs) {
    int i = blockIdx.x;
    int b = i >> 7;
    int r = b * NPG + sel[i];
    const f32x4* srcp = (const f32x4*)(x + (size_t)r * DD);
    const f32x4* aggp = (const f32x4*)(agg + (size_t)r * DD);
    f32x4 v = srcp[threadIdx.x];
    f32x4 a = aggp[threadIdx.x];
    #pragma unroll
    for (int j = 0; j < 4; ++j) v[j] += a[j];
    ((f32x4*)(xs + (size_t)i * DD))[threadIdx.x] = v;
}

extern "C" void kernel_launch(void* const* d_in, const int* in_sizes, int n_in,
                              void* d_out, int out_size, void* d_ws, size_t ws_size,
                              hipStream_t stream) {
    const float* x_in = (const float*)d_in[0];
    const int* ei = (const int*)d_in[1];
    const int* sel = (const int*)d_in[2];
    const float* W1 = (const float*)d_in[4];
    const float* b1 = (const float*)d_in[5];
    const float* W2 = (const float*)d_in[6];
    const float* b2 = (const float*)d_in[7];
    const float* g1 = (const float*)d_in[8];
    const float* be1 = (const float*)d_in[9];
    const float* g2 = (const float*)d_in[10];
    const float* be2 = (const float*)d_in[11];
    const float* fW1 = (const float*)d_in[12];
    const float* fb1 = (const float*)d_in[13];
    const float* fW2 = (const float*)d_in[14];
    const float* fb2 = (const float*)d_in[15];
    float* out = (float*)d_out;

    char* w = (char*)d_ws;
    size_t off = 0;
    auto alloc = [&](size_t bytes) -> char* {
        char* p = w + off;
        off += (bytes + 255) & ~(size_t)255;
        return p;
    };
    float* xbuf = (float*)alloc((size_t)NN * DD * 4);
    float* agg  = (float*)alloc((size_t)NN * DD * 4);
    u16* h      = (u16*)alloc((size_t)NN * DD * 2);
    u16* P      = (u16*)alloc((size_t)NN * 1024 * 2);
    u16* W1T    = (u16*)alloc((size_t)LL * 1024 * DD * 2);
    u16* W2T    = (u16*)alloc((size_t)LL * DD * DD * 2);
    u16* FW1T   = (u16*)alloc((size_t)DD * DD * 2);
    u16* FW2T   = (u16*)alloc((size_t)DD * DD * 2);
    int* cnt    = (int*)alloc((size_t)NN * 4);
    int* offs   = (int*)alloc((size_t)(NN + 1) * 4);
    int* cur    = (int*)alloc((size_t)NN * 4);
    int* ssrc   = (int*)alloc((size_t)EE * 4);
    int* sdst   = (int*)alloc((size_t)EE * 4);
    float* xs   = (float*)alloc((size_t)BBATCH * SSEL * DD * 4);
    u16* hs     = (u16*)alloc((size_t)BBATCH * SSEL * DD * 2);
    u16* uu     = (u16*)alloc((size_t)BBATCH * SSEL * DD * 2);

    const int* esrc = ei;       // edge_index[0] = x_j
    const int* edst = ei + EE;  // edge_index[1] = x_i / aggregation index

    hipMemsetAsync(cnt, 0, (size_t)NN * 4, stream);
    hist_kernel<<<EE / 256, 256, 0, stream>>>(edst, cnt);
    scan_kernel<<<1, 1024, 0, stream>>>(cnt, offs, cur);
    scatter_kernel<<<EE / 256, 256, 0, stream>>>(esrc, edst, cur, ssrc, sdst);

    // all weight conversions in 2 launches
    cvt_w1_kernel<<<dim3(16, 32, LL), 256, 0, stream>>>(W1, W1T);
    {
        CvtJobs jobs;
        jobs.s[0] = W2;
        jobs.s[1] = W2 + (size_t)DD * DD;
        jobs.s[2] = W2 + (size_t)2 * DD * DD;
        jobs.s[3] = fW1;
        jobs.s[4] = fW2;
        jobs.d[0] = W2T;
        jobs.d[1] = W2T + (size_t)DD * DD;
        jobs.d[2] = W2T + (size_t)2 * DD * DD;
        jobs.d[3] = FW1T;
        jobs.d[4] = FW2T;
        cvt_t5_kernel<<<dim3(16, 16, 5), 256, 0, stream>>>(jobs);
    }

    for (int l = 0; l < LL; ++l) {
        // x_l = x_{l-1} + agg ; h = LN(x_l) ; agg <- 0 for this layer's atomics
        ln_fused<<<NN / 4, 256, 0, stream>>>(l == 0 ? x_in : xbuf, agg, xbuf, g1, be1,
                                             h, l > 0 ? 1 : 0);
        // P = h @ [W1a-W1b | W1b] + [b1 | 0]   [8192 x 1024] bf16
        {
            dim3 grid(NN / 128, 1024 / 128);
            gemm_async<3><<<grid, 256, 0, stream>>>(
                h, W1T + (size_t)l * 1024 * DD, b1 + (size_t)l * DD, nullptr, P, DD,
                1024);
        }
        // fused: edge-combine + GEMM2 + relu + segmax-atomics into agg
        gemm_edge<<<EE / 64, 512, 0, stream>>>(
            P, ssrc, sdst, W2T + (size_t)l * DD * DD, b2 + (size_t)l * DD, agg);
    }

    gather_fused<<<BBATCH * SSEL, 128, 0, stream>>>(xbuf, agg, sel, xs);
    ln_fused<<<BBATCH * SSEL / 4, 256, 0, stream>>>(xs, nullptr, xs, g2, be2, hs, 0);
    dim3 gridf(BBATCH * SSEL / 128, DD / 128);
    gemm_async<0><<<gridf, 256, 0, stream>>>(hs, FW1T, fb1, nullptr, uu, DD, DD);
    gemm_async<1><<<gridf, 256, 0, stream>>>(uu, FW2T, fb2, xs, out, DD, DD);
}

// Round 8
// 539.343 us; speedup vs baseline: 1.1886x; 1.1886x over previous
//
#include <hip/hip_runtime.h>
#include <stdint.h>

#define NN 8192
#define DD 512
#define EE 131072
#define BBATCH 16
#define NPG 512
#define SSEL 128
#define LL 3

typedef unsigned short u16;
typedef __bf16 bf16x8 __attribute__((ext_vector_type(8)));
typedef float f32x4 __attribute__((ext_vector_type(4)));
typedef float f32x2 __attribute__((ext_vector_type(2)));
typedef u16 u16x8 __attribute__((ext_vector_type(8)));

__device__ __forceinline__ float bf2f(u16 u) {
    union { unsigned i; float f; } v; v.i = ((unsigned)u) << 16; return v.f;
}
__device__ __forceinline__ u16 f2bf(float f) {
    union { unsigned i; float f; } v; v.f = f;
    unsigned i = v.i;
    return (u16)((i + 0x7FFFu + ((i >> 16) & 1u)) >> 16);  // RNE
}

// pack two fp32 -> packed bf16x2 in one uint (lo = s0, hi = s1)
__device__ __forceinline__ unsigned pk_bf16(float s0, float s1) {
#if __has_builtin(__builtin_amdgcn_cvt_pk_bf16_f32)
    typedef __bf16 bf16x2 __attribute__((ext_vector_type(2)));
    union { bf16x2 v; unsigned u; } r;
    r.v = __builtin_amdgcn_cvt_pk_bf16_f32(s0, s1);
    return r.u;
#else
    unsigned r0 = __float_as_uint(s0);
    r0 = (r0 + 0x7FFFu + ((r0 >> 16) & 1u)) >> 16;
    unsigned r1 = __float_as_uint(s1);
    r1 = (r1 + 0x7FFFu + ((r1 >> 16) & 1u)) & 0xffff0000u;
    return r0 | r1;
#endif
}

// async global->LDS, 16B per lane, LDS dest = wave-uniform base + lane*16
__device__ __forceinline__ void async_cp16(const u16* g, u16* l) {
    __builtin_amdgcn_global_load_lds(
        (const __attribute__((address_space(1))) unsigned int*)g,
        (__attribute__((address_space(3))) unsigned int*)l, 16, 0, 0);
}

// ---------------- LayerNorm (+ optional residual-add + agg zeroing)
// 4 rows per 256-thr block (wave per row)
__global__ __launch_bounds__(256) void ln_fused(const float* __restrict__ xin,
                                                float* __restrict__ agg_io,
                                                float* __restrict__ xout,
                                                const float* __restrict__ g,
                                                const float* __restrict__ b,
                                                u16* __restrict__ h, int doAdd) {
    int row = blockIdx.x * 4 + (threadIdx.x >> 6);
    int lane = threadIdx.x & 63;
    const f32x4* x4 = (const f32x4*)(xin + (size_t)row * DD);
    f32x4 p = x4[lane * 2], q = x4[lane * 2 + 1];
    if (doAdd) {
        const f32x4* a4 = (const f32x4*)(agg_io + (size_t)row * DD);
        f32x4 pa = a4[lane * 2], qa = a4[lane * 2 + 1];
        #pragma unroll
        for (int i = 0; i < 4; ++i) { p[i] += pa[i]; q[i] += qa[i]; }
    }
    if (agg_io) {
        f32x4 z;
        #pragma unroll
        for (int i = 0; i < 4; ++i) z[i] = 0.f;
        f32x4* a4 = (f32x4*)(agg_io + (size_t)row * DD);
        a4[lane * 2] = z;
        a4[lane * 2 + 1] = z;
    }
    f32x4* xo = (f32x4*)(xout + (size_t)row * DD);
    xo[lane * 2] = p;
    xo[lane * 2 + 1] = q;
    float v[8];
    v[0] = p[0]; v[1] = p[1]; v[2] = p[2]; v[3] = p[3];
    v[4] = q[0]; v[5] = q[1]; v[6] = q[2]; v[7] = q[3];
    float s = 0.f, sq = 0.f;
    #pragma unroll
    for (int i = 0; i < 8; ++i) { s += v[i]; sq += v[i] * v[i]; }
    #pragma unroll
    for (int o = 32; o >= 1; o >>= 1) { s += __shfl_xor(s, o); sq += __shfl_xor(sq, o); }
    float mu = s * (1.f / DD);
    float var = sq * (1.f / DD) - mu * mu;
    float rs = rsqrtf(var + 1e-5f);
    int kb = lane * 8;
    u16x8 o8;
    #pragma unroll
    for (int i = 0; i < 8; ++i) o8[i] = f2bf((v[i] - mu) * rs * g[kb + i] + b[kb + i]);
    *(u16x8*)(h + (size_t)row * DD + kb) = o8;
}

// ---------------- fused gather + residual-add + LayerNorm for selected rows
// row i: r = (i>>7)*NPG + sel[i]; v = x[r] + agg[r]; xs[i] = v (residual);
// hs[i] = bf16(LN(v)). Replaces gather_fused + small ln_fused (one less pass).
__global__ __launch_bounds__(256) void ln_sel(const float* __restrict__ x,
                                              const float* __restrict__ agg,
                                              const int* __restrict__ sel,
                                              const float* __restrict__ g,
                                              const float* __restrict__ b,
                                              float* __restrict__ xs,
                                              u16* __restrict__ hs) {
    int i = blockIdx.x * 4 + (threadIdx.x >> 6);
    int lane = threadIdx.x & 63;
    int r = (i >> 7) * NPG + sel[i];
    const f32x4* x4 = (const f32x4*)(x + (size_t)r * DD);
    const f32x4* a4 = (const f32x4*)(agg + (size_t)r * DD);
    f32x4 p = x4[lane * 2], q = x4[lane * 2 + 1];
    f32x4 pa = a4[lane * 2], qa = a4[lane * 2 + 1];
    #pragma unroll
    for (int j = 0; j < 4; ++j) { p[j] += pa[j]; q[j] += qa[j]; }
    f32x4* xo = (f32x4*)(xs + (size_t)i * DD);
    xo[lane * 2] = p;
    xo[lane * 2 + 1] = q;
    float v[8];
    v[0] = p[0]; v[1] = p[1]; v[2] = p[2]; v[3] = p[3];
    v[4] = q[0]; v[5] = q[1]; v[6] = q[2]; v[7] = q[3];
    float s = 0.f, sq = 0.f;
    #pragma unroll
    for (int j = 0; j < 8; ++j) { s += v[j]; sq += v[j] * v[j]; }
    #pragma unroll
    for (int o = 32; o >= 1; o >>= 1) { s += __shfl_xor(s, o); sq += __shfl_xor(sq, o); }
    float mu = s * (1.f / DD);
    float var = sq * (1.f / DD) - mu * mu;
    float rs = rsqrtf(var + 1e-5f);
    int kb = lane * 8;
    u16x8 o8;
    #pragma unroll
    for (int j = 0; j < 8; ++j) o8[j] = f2bf((v[j] - mu) * rs * g[kb + j] + b[kb + j]);
    *(u16x8*)(hs + (size_t)i * DD + kb) = o8;
}

// ---------------- counting sort by dst
__global__ void hist_kernel(const int* __restrict__ dst, int* __restrict__ cnt) {
    int e = blockIdx.x * 256 + threadIdx.x;
    if (e < EE) atomicAdd(&cnt[dst[e]], 1);
}

__global__ __launch_bounds__(1024) void scan_kernel(const int* __restrict__ cnt,
                                                    int* __restrict__ off,
                                                    int* __restrict__ cur) {
    __shared__ int part[1024];
    int t = threadIdx.x;
    int base = t * 8;
    int loc[8]; int s = 0;
    #pragma unroll
    for (int i = 0; i < 8; ++i) { loc[i] = s; s += cnt[base + i]; }
    part[t] = s;
    __syncthreads();
    for (int o = 1; o < 1024; o <<= 1) {
        int v = part[t];
        int u = (t >= o) ? part[t - o] : 0;
        __syncthreads();
        part[t] = v + u;
        __syncthreads();
    }
    int bx = (t > 0) ? part[t - 1] : 0;
    #pragma unroll
    for (int i = 0; i < 8; ++i) { off[base + i] = bx + loc[i]; cur[base + i] = bx + loc[i]; }
    if (t == 0) off[NN] = part[1023];
}

__global__ void scatter_kernel(const int* __restrict__ src, const int* __restrict__ dst,
                               int* __restrict__ cur, int* __restrict__ ssrc,
                               int* __restrict__ sdst) {
    int e = blockIdx.x * 256 + threadIdx.x;
    if (e < EE) {
        int d = dst[e];
        int p = atomicAdd(&cur[d], 1);
        ssrc[p] = src[e];
        sdst[p] = d;
    }
}

// ---------------- 5x fused cvt+transpose for 512x512 fp32 mats -> bf16 [N][K]
struct CvtJobs {
    const float* s[5];
    u16* d[5];
};
__global__ __launch_bounds__(256) void cvt_t5_kernel(CvtJobs jobs) {
    __shared__ u16 tile[32][33];
    const float* src = jobs.s[blockIdx.z];
    u16* dstp = jobs.d[blockIdx.z];
    int bk = blockIdx.x * 32, bn = blockIdx.y * 32;
    int tx = threadIdx.x & 31, ty = threadIdx.x >> 5;  // 32 x 8
    #pragma unroll
    for (int r = 0; r < 32; r += 8)
        tile[ty + r][tx] = f2bf(src[(size_t)(bk + ty + r) * 512 + bn + tx]);
    __syncthreads();
    #pragma unroll
    for (int r = 0; r < 32; r += 8)
        dstp[(size_t)(bn + ty + r) * 512 + bk + tx] = tile[tx][ty + r];
}

// W1 fp32 [L][1024][512] -> Wcat^T bf16 [L][1024 rows][512]:
// rows 0..511 = (W1a - W1b)^T ; rows 512..1023 = W1b^T. z = layer.
__global__ __launch_bounds__(256) void cvt_w1_kernel(const float* __restrict__ W1g,
                                                     u16* __restrict__ dstg) {
    __shared__ u16 tile[32][33];
    const float* W1 = W1g + (size_t)blockIdx.z * 1024 * 512;
    u16* dstp = dstg + (size_t)blockIdx.z * 1024 * 512;
    int bk = blockIdx.x * 32, bn = blockIdx.y * 32;
    int tx = threadIdx.x & 31, ty = threadIdx.x >> 5;
    #pragma unroll
    for (int r = 0; r < 32; r += 8) {
        int k = bk + ty + r, n = bn + tx;
        float v = (n < 512) ? (W1[(size_t)k * 512 + n] - W1[(size_t)(k + 512) * 512 + n])
                            : W1[(size_t)(k + 512) * 512 + (n - 512)];
        tile[ty + r][tx] = f2bf(v);
    }
    __syncthreads();
    #pragma unroll
    for (int r = 0; r < 32; r += 8)
        dstp[(size_t)(bn + ty + r) * 512 + bk + tx] = tile[tx][ty + r];
}

// ---------------- async MFMA GEMM, 128x128 tile, 256 threads (2x2 waves)
// EMODE 0: relu(acc+bias)->bf16 ; 1: acc+bias+resid->fp32 ; 2: acc->bf16 ;
// EMODE 3: acc + (col<512 ? bias[col] : 0) -> bf16   (P-GEMM, folds b1 into Pa)
template <int EMODE>
__global__ __launch_bounds__(256) void gemm_async(
    const u16* __restrict__ A, const u16* __restrict__ BT,
    const float* __restrict__ bias, const float* __restrict__ resid,
    void* __restrict__ Cout, int K, int ldc) {
    __shared__ u16 lA[128 * 64];
    __shared__ u16 lB[128 * 64];
    const int tid = threadIdx.x;
    const int lane = tid & 63, wave = tid >> 6;
    const int wm = wave & 1, wn = wave >> 1;
    const int quad = lane >> 4, lm = lane & 15;
    const int tileM = blockIdx.x, tileN = blockIdx.y;

    const int g = (lane & 7) ^ (lane >> 3);
    const u16* ap[4];
    const u16* bp[4];
    u16* lad[4];
    u16* lbd[4];
    #pragma unroll
    for (int j = 0; j < 4; ++j) {
        int seg = wave * 4 + j;
        int rA = tileM * 128 + seg * 8 + (lane >> 3);
        int rB = tileN * 128 + seg * 8 + (lane >> 3);
        ap[j] = A + (size_t)rA * K + g * 8;
        bp[j] = BT + (size_t)rB * K + g * 8;
        lad[j] = lA + seg * 512;
        lbd[j] = lB + seg * 512;
    }

    f32x4 acc[4][4];
    #pragma unroll
    for (int mt = 0; mt < 4; ++mt)
        #pragma unroll
        for (int nt = 0; nt < 4; ++nt)
            #pragma unroll
            for (int j = 0; j < 4; ++j) acc[mt][nt][j] = 0.f;

    for (int kb = 0; kb < K; kb += 64) {
        #pragma unroll
        for (int j = 0; j < 4; ++j) {
            async_cp16(ap[j], lad[j]);
            async_cp16(bp[j], lbd[j]);
            ap[j] += 64;
            bp[j] += 64;
        }
        __syncthreads();
        #pragma unroll
        for (int kk = 0; kk < 64; kk += 32) {
            bf16x8 af[4], bfr[4];
            int gbase = (kk >> 3) + quad;
            #pragma unroll
            for (int mt = 0; mt < 4; ++mt) {
                int row = wm * 64 + mt * 16 + lm;
                af[mt] = *(const bf16x8*)(lA + row * 64 + ((gbase ^ (row & 7)) << 3));
            }
            #pragma unroll
            for (int nt = 0; nt < 4; ++nt) {
                int row = wn * 64 + nt * 16 + lm;
                bfr[nt] = *(const bf16x8*)(lB + row * 64 + ((gbase ^ (row & 7)) << 3));
            }
            #pragma unroll
            for (int mt = 0; mt < 4; ++mt)
                #pragma unroll
                for (int nt = 0; nt < 4; ++nt)
                    acc[mt][nt] = __builtin_amdgcn_mfma_f32_16x16x32_bf16(
                        af[mt], bfr[nt], acc[mt][nt], 0, 0, 0);
        }
        __syncthreads();
    }
    #pragma unroll
    for (int mt = 0; mt < 4; ++mt) {
        #pragma unroll
        for (int nt = 0; nt < 4; ++nt) {
            int col = tileN * 128 + wn * 64 + nt * 16 + lm;
            float bv;
            if (EMODE == 2) bv = 0.f;
            else if (EMODE == 3) bv = (col < 512) ? bias[col] : 0.f;
            else bv = bias[col];
            #pragma unroll
            for (int j = 0; j < 4; ++j) {
                int grow = tileM * 128 + wm * 64 + mt * 16 + quad * 4 + j;
                float v = acc[mt][nt][j] + bv;
                if (EMODE == 0) {
                    ((u16*)Cout)[(size_t)grow * ldc + col] = f2bf(fmaxf(v, 0.f));
                } else if (EMODE == 1) {
                    ((float*)Cout)[(size_t)grow * ldc + col] =
                        v + resid[(size_t)grow * ldc + col];
                } else {
                    ((u16*)Cout)[(size_t)grow * ldc + col] = f2bf(v);
                }
            }
        }
    }
}

// ---------------- fused edge GEMM, FULL-WIDTH tile: 64 edges x 512 cols,
// 512 thr (8 waves, wave-tile 64(M) x 64(N), wave = N-slice).
// R4 structure VERBATIM (best measured: 112.8us, FETCH 56MB, WRITE 32MB,
// 0 bank conflicts). Hard constraints established R1-R7:
//  * drain vmem to 0 at EVERY barrier (counted vmcnt across barriers ->
//    L2 thrash: FETCH+WRITE explode 2-6x; confirmed 3x: R2/R3/R7)
//  * regs pinned: 64 arch + 64 AGPR acc = 128/wave -> 2 blocks/CU
//  * LDS <= ~74KB -> 2 blocks/CU
//  * combine+gather once per edge (full-width; R4's win over R0)
__global__ __launch_bounds__(512, 4) void gemm_edge(
    const u16* __restrict__ P, const int* __restrict__ ssrc,
    const int* __restrict__ sdst, const u16* __restrict__ W2T,
    const float* __restrict__ b2, float* __restrict__ agg) {
    __shared__ u16 smem[64 * 64 + 512 * 64];  // lA 8KB + lB 64KB
    __shared__ int nid_l[64];
    u16* lA = smem;
    u16* lB = smem + 64 * 64;
    const int tid = threadIdx.x;
    const int lane = tid & 63, wave = tid >> 6;  // 8 waves = 8 N-slices
    const int quad = lane >> 4, lm = lane & 15;
    const int ebase = blockIdx.x * 64;

    if (tid < 64) nid_l[tid] = sdst[ebase + tid];

    const int g = (lane & 7) ^ (lane >> 3);
    // A staging: 1 segment of 8 rows per wave (64 edges total), 16B/thread
    int aoff, boff, lout;
    {
        int row = wave * 8 + (lane >> 3);
        int dn = sdst[ebase + row];
        int sn = ssrc[ebase + row];
        aoff = dn * 1024 + g * 8;
        boff = sn * 1024 + 512 + g * 8;
        lout = wave * 512 + lane * 8;
    }
    // B async staging: 8 segments of 8 rows per wave (512 rows total)
    int wbase, lbbase;
    {
        int row0 = wave * 64 + (lane >> 3);  // seg j adds 8 rows = j*8
        wbase = row0 * 512 + g * 8;          // + j*8*512 = j*4096
        lbbase = wave * 4096;                // + j*512
    }

    f32x4 acc[4][4];
    #pragma unroll
    for (int mt = 0; mt < 4; ++mt)
        #pragma unroll
        for (int nt = 0; nt < 4; ++nt)
            #pragma unroll
            for (int j = 0; j < 4; ++j) acc[mt][nt][j] = 0.f;

    for (int kb = 0; kb < 512; kb += 64) {
        // Pa/Pb gathers first (oldest in vmcnt order)...
        u16x8 ga = *(const u16x8*)(P + aoff + kb);
        u16x8 gb = *(const u16x8*)(P + boff + kb);
        // ...then W2T async copies (stay in flight while combine waits gathers)
        #pragma unroll
        for (int j = 0; j < 8; ++j)
            async_cp16(W2T + wbase + j * 4096 + kb, lB + lbbase + j * 512);
        // combine: t = relu(Pa + Pb), packed math -> lA
        {
            union { u16x8 v; unsigned w[4]; } ua, ub;
            ua.v = ga;
            ub.v = gb;
            unsigned o[4];
            #pragma unroll
            for (int q = 0; q < 4; ++q) {
                f32x2 a, c;
                a[0] = __uint_as_float(ua.w[q] << 16);
                a[1] = __uint_as_float(ua.w[q] & 0xffff0000u);
                c[0] = __uint_as_float(ub.w[q] << 16);
                c[1] = __uint_as_float(ub.w[q] & 0xffff0000u);
                f32x2 s = a + c;
#if __has_builtin(__builtin_elementwise_max)
                f32x2 z; z[0] = 0.f; z[1] = 0.f;
                s = __builtin_elementwise_max(s, z);
#else
                s[0] = fmaxf(s[0], 0.f);
                s[1] = fmaxf(s[1], 0.f);
#endif
                o[q] = pk_bf16(s[0], s[1]);
            }
            *(uint4*)(lA + lout) = make_uint4(o[0], o[1], o[2], o[3]);
        }
        __syncthreads();
        #pragma unroll
        for (int kk = 0; kk < 64; kk += 32) {
            bf16x8 af[4], bfr[4];
            int gbase = (kk >> 3) + quad;
            #pragma unroll
            for (int mt = 0; mt < 4; ++mt) {
                int row = mt * 16 + lm;  // edges 0..63
                af[mt] = *(const bf16x8*)(lA + row * 64 + ((gbase ^ (row & 7)) << 3));
            }
            #pragma unroll
            for (int nt = 0; nt < 4; ++nt) {
                int row = wave * 64 + nt * 16 + lm;  // cols 0..511
                bfr[nt] = *(const bf16x8*)(lB + row * 64 + ((gbase ^ (row & 7)) << 3));
            }
            #pragma unroll
            for (int mt = 0; mt < 4; ++mt)
                #pragma unroll
                for (int nt = 0; nt < 4; ++nt)
                    acc[mt][nt] = __builtin_amdgcn_mfma_f32_16x16x32_bf16(
                        af[mt], bfr[nt], acc[mt][nt], 0, 0, 0);
        }
        __syncthreads();
    }

    // epilogue: single pass; cbuf 64 x 520 (66.5KB, aliases lA/lB)
    u16* cbuf = smem;
    #pragma unroll
    for (int nt = 0; nt < 4; ++nt) {
        int col = wave * 64 + nt * 16 + lm;
        float bv = b2[col];
        #pragma unroll
        for (int mt = 0; mt < 4; ++mt) {
            #pragma unroll
            for (int j2 = 0; j2 < 4; ++j2) {
                int row = mt * 16 + quad * 4 + j2;  // 0..63
                cbuf[row * 520 + col] = f2bf(fmaxf(acc[mt][nt][j2] + bv, 0.f));
            }
        }
    }
    __syncthreads();
    {
        int col = tid;  // 0..511
        int cur = nid_l[0];
        float run = bf2f(cbuf[col]);
        for (int r = 1; r < 64; ++r) {
            int nd = nid_l[r];
            float v = bf2f(cbuf[r * 520 + col]);
            if (nd != cur) {
                atomicMax((unsigned int*)&agg[(size_t)cur * DD + col],
                          __float_as_uint(run));
                cur = nd;
                run = v;
            } else {
                run = fmaxf(run, v);
            }
        }
        atomicMax((unsigned int*)&agg[(size_t)cur * DD + col],
                  __float_as_uint(run));
    }
}

extern "C" void kernel_launch(void* const* d_in, const int* in_sizes, int n_in,
                              void* d_out, int out_size, void* d_ws, size_t ws_size,
                              hipStream_t stream) {
    const float* x_in = (const float*)d_in[0];
    const int* ei = (const int*)d_in[1];
    const int* sel = (const int*)d_in[2];
    const float* W1 = (const float*)d_in[4];
    const float* b1 = (const float*)d_in[5];
    const float* W2 = (const float*)d_in[6];
    const float* b2 = (const float*)d_in[7];
    const float* g1 = (const float*)d_in[8];
    const float* be1 = (const float*)d_in[9];
    const float* g2 = (const float*)d_in[10];
    const float* be2 = (const float*)d_in[11];
    const float* fW1 = (const float*)d_in[12];
    const float* fb1 = (const float*)d_in[13];
    const float* fW2 = (const float*)d_in[14];
    const float* fb2 = (const float*)d_in[15];
    float* out = (float*)d_out;

    char* w = (char*)d_ws;
    size_t off = 0;
    auto alloc = [&](size_t bytes) -> char* {
        char* p = w + off;
        off += (bytes + 255) & ~(size_t)255;
        return p;
    };
    float* xbuf = (float*)alloc((size_t)NN * DD * 4);
    float* agg  = (float*)alloc((size_t)NN * DD * 4);
    u16* h      = (u16*)alloc((size_t)NN * DD * 2);
    u16* P      = (u16*)alloc((size_t)NN * 1024 * 2);
    u16* W1T    = (u16*)alloc((size_t)LL * 1024 * DD * 2);
    u16* W2T    = (u16*)alloc((size_t)LL * DD * DD * 2);
    u16* FW1T   = (u16*)alloc((size_t)DD * DD * 2);
    u16* FW2T   = (u16*)alloc((size_t)DD * DD * 2);
    int* cnt    = (int*)alloc((size_t)NN * 4);
    int* offs   = (int*)alloc((size_t)(NN + 1) * 4);
    int* cur    = (int*)alloc((size_t)NN * 4);
    int* ssrc   = (int*)alloc((size_t)EE * 4);
    int* sdst   = (int*)alloc((size_t)EE * 4);
    float* xs   = (float*)alloc((size_t)BBATCH * SSEL * DD * 4);
    u16* hs     = (u16*)alloc((size_t)BBATCH * SSEL * DD * 2);
    u16* uu     = (u16*)alloc((size_t)BBATCH * SSEL * DD * 2);

    const int* esrc = ei;       // edge_index[0] = x_j
    const int* edst = ei + EE;  // edge_index[1] = x_i / aggregation index

    hipMemsetAsync(cnt, 0, (size_t)NN * 4, stream);
    hist_kernel<<<EE / 256, 256, 0, stream>>>(edst, cnt);
    scan_kernel<<<1, 1024, 0, stream>>>(cnt, offs, cur);
    scatter_kernel<<<EE / 256, 256, 0, stream>>>(esrc, edst, cur, ssrc, sdst);

    // all weight conversions in 2 launches
    cvt_w1_kernel<<<dim3(16, 32, LL), 256, 0, stream>>>(W1, W1T);
    {
        CvtJobs jobs;
        jobs.s[0] = W2;
        jobs.s[1] = W2 + (size_t)DD * DD;
        jobs.s[2] = W2 + (size_t)2 * DD * DD;
        jobs.s[3] = fW1;
        jobs.s[4] = fW2;
        jobs.d[0] = W2T;
        jobs.d[1] = W2T + (size_t)DD * DD;
        jobs.d[2] = W2T + (size_t)2 * DD * DD;
        jobs.d[3] = FW1T;
        jobs.d[4] = FW2T;
        cvt_t5_kernel<<<dim3(16, 16, 5), 256, 0, stream>>>(jobs);
    }

    for (int l = 0; l < LL; ++l) {
        // x_l = x_{l-1} + agg ; h = LN(x_l) ; agg <- 0 for this layer's atomics
        ln_fused<<<NN / 4, 256, 0, stream>>>(l == 0 ? x_in : xbuf, agg, xbuf, g1, be1,
                                             h, l > 0 ? 1 : 0);
        // P = h @ [W1a-W1b | W1b] + [b1 | 0]   [8192 x 1024] bf16
        {
            dim3 grid(NN / 128, 1024 / 128);
            gemm_async<3><<<grid, 256, 0, stream>>>(
                h, W1T + (size_t)l * 1024 * DD, b1 + (size_t)l * DD, nullptr, P, DD,
                1024);
        }
        // fused: edge-combine + GEMM2 + relu + segmax-atomics into agg
        gemm_edge<<<EE / 64, 512, 0, stream>>>(
            P, ssrc, sdst, W2T + (size_t)l * DD * DD, b2 + (size_t)l * DD, agg);
    }

    // fused gather + residual-add + LN for selected rows (one pass)
    ln_sel<<<BBATCH * SSEL / 4, 256, 0, stream>>>(xbuf, agg, sel, g2, be2, xs, hs);
    dim3 gridf(BBATCH * SSEL / 128, DD / 128);
    gemm_async<0><<<gridf, 256, 0, stream>>>(hs, FW1T, fb1, nullptr, uu, DD, DD);
    gemm_async<1><<<gridf, 256, 0, stream>>>(uu, FW2T, fb2, xs, out, DD, DD);
}

// Round 9
// 537.946 us; speedup vs baseline: 1.1917x; 1.0026x over previous
//
#include <hip/hip_runtime.h>
#include <stdint.h>

#define NN 8192
#define DD 512
#define EE 131072
#define BBATCH 16
#define NPG 512
#define SSEL 128
#define LL 3

typedef unsigned short u16;
typedef __bf16 bf16x8 __attribute__((ext_vector_type(8)));
typedef float f32x4 __attribute__((ext_vector_type(4)));
typedef float f32x2 __attribute__((ext_vector_type(2)));
typedef u16 u16x8 __attribute__((ext_vector_type(8)));

__device__ __forceinline__ float bf2f(u16 u) {
    union { unsigned i; float f; } v; v.i = ((unsigned)u) << 16; return v.f;
}
__device__ __forceinline__ u16 f2bf(float f) {
    union { unsigned i; float f; } v; v.f = f;
    unsigned i = v.i;
    return (u16)((i + 0x7FFFu + ((i >> 16) & 1u)) >> 16);  // RNE
}

// pack two fp32 -> packed bf16x2 in one uint (lo = s0, hi = s1)
__device__ __forceinline__ unsigned pk_bf16(float s0, float s1) {
#if __has_builtin(__builtin_amdgcn_cvt_pk_bf16_f32)
    typedef __bf16 bf16x2 __attribute__((ext_vector_type(2)));
    union { bf16x2 v; unsigned u; } r;
    r.v = __builtin_amdgcn_cvt_pk_bf16_f32(s0, s1);
    return r.u;
#else
    unsigned r0 = __float_as_uint(s0);
    r0 = (r0 + 0x7FFFu + ((r0 >> 16) & 1u)) >> 16;
    unsigned r1 = __float_as_uint(s1);
    r1 = (r1 + 0x7FFFu + ((r1 >> 16) & 1u)) & 0xffff0000u;
    return r0 | r1;
#endif
}

// async global->LDS, 16B per lane, LDS dest = wave-uniform base + lane*16
__device__ __forceinline__ void async_cp16(const u16* g, u16* l) {
    __builtin_amdgcn_global_load_lds(
        (const __attribute__((address_space(1))) unsigned int*)g,
        (__attribute__((address_space(3))) unsigned int*)l, 16, 0, 0);
}

// ---------------- LayerNorm (+ optional residual-add + agg zeroing)
// 4 rows per 256-thr block (wave per row)
__global__ __launch_bounds__(256) void ln_fused(const float* __restrict__ xin,
                                                float* __restrict__ agg_io,
                                                float* __restrict__ xout,
                                                const float* __restrict__ g,
                                                const float* __restrict__ b,
                                                u16* __restrict__ h, int doAdd) {
    int row = blockIdx.x * 4 + (threadIdx.x >> 6);
    int lane = threadIdx.x & 63;
    const f32x4* x4 = (const f32x4*)(xin + (size_t)row * DD);
    f32x4 p = x4[lane * 2], q = x4[lane * 2 + 1];
    if (doAdd) {
        const f32x4* a4 = (const f32x4*)(agg_io + (size_t)row * DD);
        f32x4 pa = a4[lane * 2], qa = a4[lane * 2 + 1];
        #pragma unroll
        for (int i = 0; i < 4; ++i) { p[i] += pa[i]; q[i] += qa[i]; }
    }
    if (agg_io) {
        f32x4 z;
        #pragma unroll
        for (int i = 0; i < 4; ++i) z[i] = 0.f;
        f32x4* a4 = (f32x4*)(agg_io + (size_t)row * DD);
        a4[lane * 2] = z;
        a4[lane * 2 + 1] = z;
    }
    f32x4* xo = (f32x4*)(xout + (size_t)row * DD);
    xo[lane * 2] = p;
    xo[lane * 2 + 1] = q;
    float v[8];
    v[0] = p[0]; v[1] = p[1]; v[2] = p[2]; v[3] = p[3];
    v[4] = q[0]; v[5] = q[1]; v[6] = q[2]; v[7] = q[3];
    float s = 0.f, sq = 0.f;
    #pragma unroll
    for (int i = 0; i < 8; ++i) { s += v[i]; sq += v[i] * v[i]; }
    #pragma unroll
    for (int o = 32; o >= 1; o >>= 1) { s += __shfl_xor(s, o); sq += __shfl_xor(sq, o); }
    float mu = s * (1.f / DD);
    float var = sq * (1.f / DD) - mu * mu;
    float rs = rsqrtf(var + 1e-5f);
    int kb = lane * 8;
    u16x8 o8;
    #pragma unroll
    for (int i = 0; i < 8; ++i) o8[i] = f2bf((v[i] - mu) * rs * g[kb + i] + b[kb + i]);
    *(u16x8*)(h + (size_t)row * DD + kb) = o8;
}

// ---------------- fused gather + residual-add + LayerNorm for selected rows
__global__ __launch_bounds__(256) void ln_sel(const float* __restrict__ x,
                                              const float* __restrict__ agg,
                                              const int* __restrict__ sel,
                                              const float* __restrict__ g,
                                              const float* __restrict__ b,
                                              float* __restrict__ xs,
                                              u16* __restrict__ hs) {
    int i = blockIdx.x * 4 + (threadIdx.x >> 6);
    int lane = threadIdx.x & 63;
    int r = (i >> 7) * NPG + sel[i];
    const f32x4* x4 = (const f32x4*)(x + (size_t)r * DD);
    const f32x4* a4 = (const f32x4*)(agg + (size_t)r * DD);
    f32x4 p = x4[lane * 2], q = x4[lane * 2 + 1];
    f32x4 pa = a4[lane * 2], qa = a4[lane * 2 + 1];
    #pragma unroll
    for (int j = 0; j < 4; ++j) { p[j] += pa[j]; q[j] += qa[j]; }
    f32x4* xo = (f32x4*)(xs + (size_t)i * DD);
    xo[lane * 2] = p;
    xo[lane * 2 + 1] = q;
    float v[8];
    v[0] = p[0]; v[1] = p[1]; v[2] = p[2]; v[3] = p[3];
    v[4] = q[0]; v[5] = q[1]; v[6] = q[2]; v[7] = q[3];
    float s = 0.f, sq = 0.f;
    #pragma unroll
    for (int j = 0; j < 8; ++j) { s += v[j]; sq += v[j] * v[j]; }
    #pragma unroll
    for (int o = 32; o >= 1; o >>= 1) { s += __shfl_xor(s, o); sq += __shfl_xor(sq, o); }
    float mu = s * (1.f / DD);
    float var = sq * (1.f / DD) - mu * mu;
    float rs = rsqrtf(var + 1e-5f);
    int kb = lane * 8;
    u16x8 o8;
    #pragma unroll
    for (int j = 0; j < 8; ++j) o8[j] = f2bf((v[j] - mu) * rs * g[kb + j] + b[kb + j]);
    *(u16x8*)(hs + (size_t)i * DD + kb) = o8;
}

// ---------------- counting sort by dst
__global__ void hist_kernel(const int* __restrict__ dst, int* __restrict__ cnt) {
    int e = blockIdx.x * 256 + threadIdx.x;
    if (e < EE) atomicAdd(&cnt[dst[e]], 1);
}

__global__ __launch_bounds__(1024) void scan_kernel(const int* __restrict__ cnt,
                                                    int* __restrict__ off,
                                                    int* __restrict__ cur) {
    __shared__ int part[1024];
    int t = threadIdx.x;
    int base = t * 8;
    int loc[8]; int s = 0;
    #pragma unroll
    for (int i = 0; i < 8; ++i) { loc[i] = s; s += cnt[base + i]; }
    part[t] = s;
    __syncthreads();
    for (int o = 1; o < 1024; o <<= 1) {
        int v = part[t];
        int u = (t >= o) ? part[t - o] : 0;
        __syncthreads();
        part[t] = v + u;
        __syncthreads();
    }
    int bx = (t > 0) ? part[t - 1] : 0;
    #pragma unroll
    for (int i = 0; i < 8; ++i) { off[base + i] = bx + loc[i]; cur[base + i] = bx + loc[i]; }
    if (t == 0) off[NN] = part[1023];
}

__global__ void scatter_kernel(const int* __restrict__ src, const int* __restrict__ dst,
                               int* __restrict__ cur, int* __restrict__ ssrc,
                               int* __restrict__ sdst) {
    int e = blockIdx.x * 256 + threadIdx.x;
    if (e < EE) {
        int d = dst[e];
        int p = atomicAdd(&cur[d], 1);
        ssrc[p] = src[e];
        sdst[p] = d;
    }
}

// ---------------- 5x fused cvt+transpose for 512x512 fp32 mats -> bf16 [N][K]
struct CvtJobs {
    const float* s[5];
    u16* d[5];
};
__global__ __launch_bounds__(256) void cvt_t5_kernel(CvtJobs jobs) {
    __shared__ u16 tile[32][33];
    const float* src = jobs.s[blockIdx.z];
    u16* dstp = jobs.d[blockIdx.z];
    int bk = blockIdx.x * 32, bn = blockIdx.y * 32;
    int tx = threadIdx.x & 31, ty = threadIdx.x >> 5;  // 32 x 8
    #pragma unroll
    for (int r = 0; r < 32; r += 8)
        tile[ty + r][tx] = f2bf(src[(size_t)(bk + ty + r) * 512 + bn + tx]);
    __syncthreads();
    #pragma unroll
    for (int r = 0; r < 32; r += 8)
        dstp[(size_t)(bn + ty + r) * 512 + bk + tx] = tile[tx][ty + r];
}

// W1 fp32 [L][1024][512] -> Wcat^T bf16 [L][1024 rows][512]:
// rows 0..511 = (W1a - W1b)^T ; rows 512..1023 = W1b^T. z = layer.
__global__ __launch_bounds__(256) void cvt_w1_kernel(const float* __restrict__ W1g,
                                                     u16* __restrict__ dstg) {
    __shared__ u16 tile[32][33];
    const float* W1 = W1g + (size_t)blockIdx.z * 1024 * 512;
    u16* dstp = dstg + (size_t)blockIdx.z * 1024 * 512;
    int bk = blockIdx.x * 32, bn = blockIdx.y * 32;
    int tx = threadIdx.x & 31, ty = threadIdx.x >> 5;
    #pragma unroll
    for (int r = 0; r < 32; r += 8) {
        int k = bk + ty + r, n = bn + tx;
        float v = (n < 512) ? (W1[(size_t)k * 512 + n] - W1[(size_t)(k + 512) * 512 + n])
                            : W1[(size_t)(k + 512) * 512 + (n - 512)];
        tile[ty + r][tx] = f2bf(v);
    }
    __syncthreads();
    #pragma unroll
    for (int r = 0; r < 32; r += 8)
        dstp[(size_t)(bn + ty + r) * 512 + bk + tx] = tile[tx][ty + r];
}

// ---------------- async MFMA GEMM, 128x128 tile, 256 threads (2x2 waves)
// EMODE 0: relu(acc+bias)->bf16 ; 1: acc+bias+resid->fp32 ; 2: acc->bf16 ;
// EMODE 3: acc + (col<512 ? bias[col] : 0) -> bf16   (P-GEMM, folds b1 into Pa)
template <int EMODE>
__global__ __launch_bounds__(256) void gemm_async(
    const u16* __restrict__ A, const u16* __restrict__ BT,
    const float* __restrict__ bias, const float* __restrict__ resid,
    void* __restrict__ Cout, int K, int ldc) {
    __shared__ u16 lA[128 * 64];
    __shared__ u16 lB[128 * 64];
    const int tid = threadIdx.x;
    const int lane = tid & 63, wave = tid >> 6;
    const int wm = wave & 1, wn = wave >> 1;
    const int quad = lane >> 4, lm = lane & 15;
    const int tileM = blockIdx.x, tileN = blockIdx.y;

    const int g = (lane & 7) ^ (lane >> 3);
    const u16* ap[4];
    const u16* bp[4];
    u16* lad[4];
    u16* lbd[4];
    #pragma unroll
    for (int j = 0; j < 4; ++j) {
        int seg = wave * 4 + j;
        int rA = tileM * 128 + seg * 8 + (lane >> 3);
        int rB = tileN * 128 + seg * 8 + (lane >> 3);
        ap[j] = A + (size_t)rA * K + g * 8;
        bp[j] = BT + (size_t)rB * K + g * 8;
        lad[j] = lA + seg * 512;
        lbd[j] = lB + seg * 512;
    }

    f32x4 acc[4][4];
    #pragma unroll
    for (int mt = 0; mt < 4; ++mt)
        #pragma unroll
        for (int nt = 0; nt < 4; ++nt)
            #pragma unroll
            for (int j = 0; j < 4; ++j) acc[mt][nt][j] = 0.f;

    for (int kb = 0; kb < K; kb += 64) {
        #pragma unroll
        for (int j = 0; j < 4; ++j) {
            async_cp16(ap[j], lad[j]);
            async_cp16(bp[j], lbd[j]);
            ap[j] += 64;
            bp[j] += 64;
        }
        __syncthreads();
        #pragma unroll
        for (int kk = 0; kk < 64; kk += 32) {
            bf16x8 af[4], bfr[4];
            int gbase = (kk >> 3) + quad;
            #pragma unroll
            for (int mt = 0; mt < 4; ++mt) {
                int row = wm * 64 + mt * 16 + lm;
                af[mt] = *(const bf16x8*)(lA + row * 64 + ((gbase ^ (row & 7)) << 3));
            }
            #pragma unroll
            for (int nt = 0; nt < 4; ++nt) {
                int row = wn * 64 + nt * 16 + lm;
                bfr[nt] = *(const bf16x8*)(lB + row * 64 + ((gbase ^ (row & 7)) << 3));
            }
            #pragma unroll
            for (int mt = 0; mt < 4; ++mt)
                #pragma unroll
                for (int nt = 0; nt < 4; ++nt)
                    acc[mt][nt] = __builtin_amdgcn_mfma_f32_16x16x32_bf16(
                        af[mt], bfr[nt], acc[mt][nt], 0, 0, 0);
        }
        __syncthreads();
    }
    #pragma unroll
    for (int mt = 0; mt < 4; ++mt) {
        #pragma unroll
        for (int nt = 0; nt < 4; ++nt) {
            int col = tileN * 128 + wn * 64 + nt * 16 + lm;
            float bv;
            if (EMODE == 2) bv = 0.f;
            else if (EMODE == 3) bv = (col < 512) ? bias[col] : 0.f;
            else bv = bias[col];
            #pragma unroll
            for (int j = 0; j < 4; ++j) {
                int grow = tileM * 128 + wm * 64 + mt * 16 + quad * 4 + j;
                float v = acc[mt][nt][j] + bv;
                if (EMODE == 0) {
                    ((u16*)Cout)[(size_t)grow * ldc + col] = f2bf(fmaxf(v, 0.f));
                } else if (EMODE == 1) {
                    ((float*)Cout)[(size_t)grow * ldc + col] =
                        v + resid[(size_t)grow * ldc + col];
                } else {
                    ((u16*)Cout)[(size_t)grow * ldc + col] = f2bf(v);
                }
            }
        }
    }
}

// ---------------- fused edge GEMM, 128 edges x 512 cols, 1024 thr (16 waves,
// 2M x 8N grid of 64x64 wave tiles).
// Round-16: R4/R8 schedule VERBATIM (gathers -> W2T asyncs -> combine ->
// __syncthreads -> MFMA -> __syncthreads; full vmem drain at every barrier).
// The change is M=128 via a 1024-thread block: halves the number of blocks
// -> each W2T (512KB) streamed through L2 by 1024 blocks instead of 2048
// -> per-CU W2T L2 traffic halves (~31us -> ~15us of the 111us). Wave-level
// TLP per CU is UNCHANGED (16 waves = was 2 blocks x 8 waves) - this is the
// difference from R1's failed 1-block variant which halved wave count.
//  * regs: 64 arch + 64 AGPR acc = 128/wave -> 16 waves/CU (1 block)
//  * LDS: lA 16KB + lB 64KB + nid 0.5KB = 80.5KB (1 block/CU anyway)
//  * epilogue: 2 passes of 64 rows (proven R0 form), cbuf 64x520 aliased
__global__ __launch_bounds__(1024, 4) void gemm_edge(
    const u16* __restrict__ P, const int* __restrict__ ssrc,
    const int* __restrict__ sdst, const u16* __restrict__ W2T,
    const float* __restrict__ b2, float* __restrict__ agg) {
    __shared__ u16 smem[128 * 64 + 512 * 64];  // lA 16KB + lB 64KB
    __shared__ int nid_l[128];
    u16* lA = smem;
    u16* lB = smem + 128 * 64;
    const int tid = threadIdx.x;
    const int lane = tid & 63, wave = tid >> 6;  // 16 waves
    const int wm = wave >> 3, wn = wave & 7;     // 2M x 8N, wave tile 64x64
    const int quad = lane >> 4, lm = lane & 15;
    const int ebase = blockIdx.x * 128;

    if (tid < 128) nid_l[tid] = sdst[ebase + tid];

    const int g = (lane & 7) ^ (lane >> 3);
    // A staging: 8 rows per wave (128 edges total), 16B/thread
    int aoff, boff, lout;
    {
        int row = wave * 8 + (lane >> 3);
        int dn = sdst[ebase + row];
        int sn = ssrc[ebase + row];
        aoff = dn * 1024 + g * 8;
        boff = sn * 1024 + 512 + g * 8;
        lout = wave * 512 + lane * 8;  // row*64 + slot*8, slot holds granule g
    }
    // B async staging: 4 segments of 8 rows per wave (512 rows total)
    int wbase, lbbase;
    {
        int row0 = wave * 32 + (lane >> 3);  // seg j adds 8 rows = j*8
        wbase = row0 * 512 + g * 8;          // + j*4096 + kb
        lbbase = wave * 2048;                // + j*512
    }

    f32x4 acc[4][4];
    #pragma unroll
    for (int mt = 0; mt < 4; ++mt)
        #pragma unroll
        for (int nt = 0; nt < 4; ++nt)
            #pragma unroll
            for (int j = 0; j < 4; ++j) acc[mt][nt][j] = 0.f;

    for (int kb = 0; kb < 512; kb += 64) {
        // Pa/Pb gathers first (oldest in vmcnt order)...
        u16x8 ga = *(const u16x8*)(P + aoff + kb);
        u16x8 gb = *(const u16x8*)(P + boff + kb);
        // ...then W2T async copies (stay in flight while combine waits gathers)
        #pragma unroll
        for (int j = 0; j < 4; ++j)
            async_cp16(W2T + wbase + j * 4096 + kb, lB + lbbase + j * 512);
        // combine: t = relu(Pa + Pb), packed math -> lA
        {
            union { u16x8 v; unsigned w[4]; } ua, ub;
            ua.v = ga;
            ub.v = gb;
            unsigned o[4];
            #pragma unroll
            for (int q = 0; q < 4; ++q) {
                f32x2 a, c;
                a[0] = __uint_as_float(ua.w[q] << 16);
                a[1] = __uint_as_float(ua.w[q] & 0xffff0000u);
                c[0] = __uint_as_float(ub.w[q] << 16);
                c[1] = __uint_as_float(ub.w[q] & 0xffff0000u);
                f32x2 s = a + c;
#if __has_builtin(__builtin_elementwise_max)
                f32x2 z; z[0] = 0.f; z[1] = 0.f;
                s = __builtin_elementwise_max(s, z);
#else
                s[0] = fmaxf(s[0], 0.f);
                s[1] = fmaxf(s[1], 0.f);
#endif
                o[q] = pk_bf16(s[0], s[1]);
            }
            *(uint4*)(lA + lout) = make_uint4(o[0], o[1], o[2], o[3]);
        }
        __syncthreads();
        #pragma unroll
        for (int kk = 0; kk < 64; kk += 32) {
            bf16x8 af[4], bfr[4];
            int gbase = (kk >> 3) + quad;
            #pragma unroll
            for (int mt = 0; mt < 4; ++mt) {
                int row = wm * 64 + mt * 16 + lm;  // edges 0..127
                af[mt] = *(const bf16x8*)(lA + row * 64 + ((gbase ^ (row & 7)) << 3));
            }
            #pragma unroll
            for (int nt = 0; nt < 4; ++nt) {
                int row = wn * 64 + nt * 16 + lm;  // cols 0..511
                bfr[nt] = *(const bf16x8*)(lB + row * 64 + ((gbase ^ (row & 7)) << 3));
            }
            #pragma unroll
            for (int mt = 0; mt < 4; ++mt)
                #pragma unroll
                for (int nt = 0; nt < 4; ++nt)
                    acc[mt][nt] = __builtin_amdgcn_mfma_f32_16x16x32_bf16(
                        af[mt], bfr[nt], acc[mt][nt], 0, 0, 0);
        }
        __syncthreads();
    }

    // epilogue: 2 passes of 64 rows; cbuf 64 x 520 (66.5KB, aliases lA/lB)
    u16* cbuf = smem;
    for (int p = 0; p < 2; ++p) {
        if (wm == p) {
            #pragma unroll
            for (int nt = 0; nt < 4; ++nt) {
                int col = wn * 64 + nt * 16 + lm;
                float bv = b2[col];
                #pragma unroll
                for (int mt = 0; mt < 4; ++mt) {
                    #pragma unroll
                    for (int j2 = 0; j2 < 4; ++j2) {
                        int row = mt * 16 + quad * 4 + j2;  // 0..63 within pass
                        cbuf[row * 520 + col] = f2bf(fmaxf(acc[mt][nt][j2] + bv, 0.f));
                    }
                }
            }
        }
        __syncthreads();
        {
            int col = tid & 511;
            int r0 = (tid >> 9) * 32;  // 0 or 32 within the 64-row pass
            int gr0 = p * 64 + r0;     // row within the 128-edge tile
            int cur = nid_l[gr0];
            float run = bf2f(cbuf[r0 * 520 + col]);
            for (int r = 1; r < 32; ++r) {
                int nd = nid_l[gr0 + r];
                float v = bf2f(cbuf[(r0 + r) * 520 + col]);
                if (nd != cur) {
                    atomicMax((unsigned int*)&agg[(size_t)cur * DD + col],
                              __float_as_uint(run));
                    cur = nd;
                    run = v;
                } else {
                    run = fmaxf(run, v);
                }
            }
            atomicMax((unsigned int*)&agg[(size_t)cur * DD + col],
                      __float_as_uint(run));
        }
        __syncthreads();
    }
}

extern "C" void kernel_launch(void* const* d_in, const int* in_sizes, int n_in,
                              void* d_out, int out_size, void* d_ws, size_t ws_size,
                              hipStream_t stream) {
    const float* x_in = (const float*)d_in[0];
    const int* ei = (const int*)d_in[1];
    const int* sel = (const int*)d_in[2];
    const float* W1 = (const float*)d_in[4];
    const float* b1 = (const float*)d_in[5];
    const float* W2 = (const float*)d_in[6];
    const float* b2 = (const float*)d_in[7];
    const float* g1 = (const float*)d_in[8];
    const float* be1 = (const float*)d_in[9];
    const float* g2 = (const float*)d_in[10];
    const float* be2 = (const float*)d_in[11];
    const float* fW1 = (const float*)d_in[12];
    const float* fb1 = (const float*)d_in[13];
    const float* fW2 = (const float*)d_in[14];
    const float* fb2 = (const float*)d_in[15];
    float* out = (float*)d_out;

    char* w = (char*)d_ws;
    size_t off = 0;
    auto alloc = [&](size_t bytes) -> char* {
        char* p = w + off;
        off += (bytes + 255) & ~(size_t)255;
        return p;
    };
    float* xbuf = (float*)alloc((size_t)NN * DD * 4);
    float* agg  = (float*)alloc((size_t)NN * DD * 4);
    u16* h      = (u16*)alloc((size_t)NN * DD * 2);
    u16* P      = (u16*)alloc((size_t)NN * 1024 * 2);
    u16* W1T    = (u16*)alloc((size_t)LL * 1024 * DD * 2);
    u16* W2T    = (u16*)alloc((size_t)LL * DD * DD * 2);
    u16* FW1T   = (u16*)alloc((size_t)DD * DD * 2);
    u16* FW2T   = (u16*)alloc((size_t)DD * DD * 2);
    int* cnt    = (int*)alloc((size_t)NN * 4);
    int* offs   = (int*)alloc((size_t)(NN + 1) * 4);
    int* cur    = (int*)alloc((size_t)NN * 4);
    int* ssrc   = (int*)alloc((size_t)EE * 4);
    int* sdst   = (int*)alloc((size_t)EE * 4);
    float* xs   = (float*)alloc((size_t)BBATCH * SSEL * DD * 4);
    u16* hs     = (u16*)alloc((size_t)BBATCH * SSEL * DD * 2);
    u16* uu     = (u16*)alloc((size_t)BBATCH * SSEL * DD * 2);

    const int* esrc = ei;       // edge_index[0] = x_j
    const int* edst = ei + EE;  // edge_index[1] = x_i / aggregation index

    hipMemsetAsync(cnt, 0, (size_t)NN * 4, stream);
    hist_kernel<<<EE / 256, 256, 0, stream>>>(edst, cnt);
    scan_kernel<<<1, 1024, 0, stream>>>(cnt, offs, cur);
    scatter_kernel<<<EE / 256, 256, 0, stream>>>(esrc, edst, cur, ssrc, sdst);

    // all weight conversions in 2 launches
    cvt_w1_kernel<<<dim3(16, 32, LL), 256, 0, stream>>>(W1, W1T);
    {
        CvtJobs jobs;
        jobs.s[0] = W2;
        jobs.s[1] = W2 + (size_t)DD * DD;
        jobs.s[2] = W2 + (size_t)2 * DD * DD;
        jobs.s[3] = fW1;
        jobs.s[4] = fW2;
        jobs.d[0] = W2T;
        jobs.d[1] = W2T + (size_t)DD * DD;
        jobs.d[2] = W2T + (size_t)2 * DD * DD;
        jobs.d[3] = FW1T;
        jobs.d[4] = FW2T;
        cvt_t5_kernel<<<dim3(16, 16, 5), 256, 0, stream>>>(jobs);
    }

    for (int l = 0; l < LL; ++l) {
        // x_l = x_{l-1} + agg ; h = LN(x_l) ; agg <- 0 for this layer's atomics
        ln_fused<<<NN / 4, 256, 0, stream>>>(l == 0 ? x_in : xbuf, agg, xbuf, g1, be1,
                                             h, l > 0 ? 1 : 0);
        // P = h @ [W1a-W1b | W1b] + [b1 | 0]   [8192 x 1024] bf16
        {
            dim3 grid(NN / 128, 1024 / 128);
            gemm_async<3><<<grid, 256, 0, stream>>>(
                h, W1T + (size_t)l * 1024 * DD, b1 + (size_t)l * DD, nullptr, P, DD,
                1024);
        }
        // fused: edge-combine + GEMM2 + relu + segmax-atomics into agg
        gemm_edge<<<EE / 128, 1024, 0, stream>>>(
            P, ssrc, sdst, W2T + (size_t)l * DD * DD, b2 + (size_t)l * DD, agg);
    }

    // fused gather + residual-add + LN for selected rows (one pass)
    ln_sel<<<BBATCH * SSEL / 4, 256, 0, stream>>>(xbuf, agg, sel, g2, be2, xs, hs);
    dim3 gridf(BBATCH * SSEL / 128, DD / 128);
    gemm_async<0><<<gridf, 256, 0, stream>>>(hs, FW1T, fb1, nullptr, uu, DD, DD);
    gemm_async<1><<<gridf, 256, 0, stream>>>(uu, FW2T, fb2, xs, out, DD, DD);
}